// Round 10
// baseline (164.061 us; speedup 1.0000x reference)
//
#include <hip/hip_runtime.h>
#include <math.h>

// SoftKConv, round 10.
// r9 post-mortem: still latency-bound — one node per wave means every node
// pays full gather+chain latency with only ~3 waves/SIMD of TLP. r10:
// persistent waves, grid-stride over ~16 nodes/wave, software-pipelined:
//   - next node's idx/tkw loads issued at iteration top
//   - next node's 8 fragment loads issued mid-iteration (gram gives ~300cyc
//     of cover for the idx load; dagg/softmax/epilogue tail covers frags)
//   - ev[] hoist dropped (keeps VGPR <= 128 with frag+frag_n double buffer)
// gemm: 64-thread blocks (1563 units, no tail quantization).
// All r8/r9-proven pieces kept: single gather, fragment-order LDS staging,
// fdot2 sq, homog 9th MFMA, bpermute w, fused softmax, rbuf broadcast,
// ds_read2 epilogue. Tripwire: WRITE_SIZE must stay 25 MB (no spill).

typedef __attribute__((ext_vector_type(2)))  _Float16 half2v;
typedef __attribute__((ext_vector_type(4)))  _Float16 half4v;
typedef __attribute__((ext_vector_type(8)))  _Float16 half8;
typedef __attribute__((ext_vector_type(16))) float    f32x16;

#define NK   32
#define DIM  128
// LDS: half-offset(k,d) = ((d>>3)*33 + k)*8 + (d&7); 16*33*8 = 4224 halves.
#define FKT_SZ 4224

// ---------------- Kernel 0: WT[n][k] = (f16) W[k][n] -----------------------
__global__ __launch_bounds__(256) void prep(const float* __restrict__ W,
                                            _Float16* __restrict__ WT) {
    int t  = blockIdx.x * 256 + threadIdx.x;   // 0..16383
    int nn = t >> 7, k = t & 127;
    WT[t] = (_Float16)W[k * 128 + nn];
}

// ---------------- Kernel 1: h = feat @ W -> f16, MFMA ----------------------
// 64-thread blocks (1 wave, 32 rows) for fine-grained scheduling.
__global__ __launch_bounds__(64) void gemm128(
    const float* __restrict__ A, const _Float16* __restrict__ WT,
    _Float16* __restrict__ Hq, int n)
{
    const int lane = threadIdx.x;
    const int l31  = lane & 31;
    const int hf   = lane >> 5;

    const int row  = blockIdx.x * 32 + l31;
    const int rowc = row < n ? row : n - 1;

    f32x16 acc[4];
#pragma unroll
    for (int t = 0; t < 4; ++t)
#pragma unroll
        for (int i = 0; i < 16; ++i) acc[t][i] = 0.0f;

    const float* ap = A + (size_t)rowc * 128 + 8 * hf;
#pragma unroll
    for (int s = 0; s < 8; ++s) {
        float4 b0 = *reinterpret_cast<const float4*>(ap + 16 * s);
        float4 b1 = *reinterpret_cast<const float4*>(ap + 16 * s + 4);
        half8 bf;
        bf[0] = (_Float16)b0.x; bf[1] = (_Float16)b0.y;
        bf[2] = (_Float16)b0.z; bf[3] = (_Float16)b0.w;
        bf[4] = (_Float16)b1.x; bf[5] = (_Float16)b1.y;
        bf[6] = (_Float16)b1.z; bf[7] = (_Float16)b1.w;
#pragma unroll
        for (int t = 0; t < 4; ++t) {
            half8 af = *reinterpret_cast<const half8*>(
                WT + (size_t)(l31 + 32 * t) * 128 + 16 * s + 8 * hf);
            acc[t] = __builtin_amdgcn_mfma_f32_32x32x16_f16(af, bf, acc[t], 0, 0, 0);
        }
    }

    if (row < n) {
        _Float16* hp = Hq + (size_t)row * 128;
#pragma unroll
        for (int t = 0; t < 4; ++t)
#pragma unroll
            for (int g = 0; g < 4; ++g) {
                half4v hv;
#pragma unroll
                for (int q = 0; q < 4; ++q) hv[q] = (_Float16)acc[t][4 * g + q];
                *reinterpret_cast<half4v*>(hp + 32 * t + 8 * g + 4 * hf) = hv;
            }
    }
}

// ---------------- Kernel 2: per-node soft medoid, persistent+pipelined -----
// 128 threads = 2 waves; each wave grid-strides over nodes independently
// (no barriers, per-wave LDS region).
__global__ __launch_bounds__(128, 4) void softk(
    const _Float16* __restrict__ hq, const float* __restrict__ bias,
    const float* __restrict__ tkw, const int* __restrict__ idx,
    float* __restrict__ out, int n)
{
    __shared__ __align__(16) _Float16 fkT[2][FKT_SZ];   // 16896 B
    __shared__ __align__(16) float    rbuf[2][NK];      //   256 B

    const int wave = threadIdx.x >> 6;
    const int lane = threadIdx.x & 63;
    const int l31  = lane & 31;
    const int hf   = lane >> 5;
    const int pbase = (lane & 32) + ((lane & 32) >> 3);  // hf=0 -> 0, hf=1 -> 36

    // loop-invariant per-lane state
    const int d0 = 2 * lane;
    const float2 bv = *reinterpret_cast<const float2*>(bias + d0);
    const _Float16* fb = &fkT[wave][((d0 >> 3) * 33) * 8 + (d0 & 7)];
    const float4* rb = reinterpret_cast<const float4*>(&rbuf[wave][0]);

    const int stride = gridDim.x * 2;
    int nd = blockIdx.x * 2 + wave;
    if (nd >= n) return;                    // wave-uniform; no barriers used

    // ---- prologue: loads for first node ----
    int   vid = idx[(size_t)nd * NK + l31];
    float tw  = tkw[(size_t)nd * NK + l31];
    int   mkc = (vid < 0) ? 1 : 0;
    float wc  = mkc ? 0.0f : tw;
    half8 frag[8];
    {
        const int idr = mkc ? 0 : vid;
        const half8* bp = reinterpret_cast<const half8*>(hq + (size_t)idr * DIM);
#pragma unroll
        for (int s = 0; s < 8; ++s) frag[s] = bp[2 * s + hf];
    }

    while (true) {
        const int  ndn = nd + stride;
        const bool hn  = ndn < n;

        // pipeline stage 1: next node's idx/tkw (cover = staging+gram+fdot2)
        int vid_n = 0; float tw_n = 0.0f;
        if (hn) {
            vid_n = idx[(size_t)ndn * NK + l31];
            tw_n  = tkw[(size_t)ndn * NK + l31];
        }

        // ---- stage frags to LDS, fragment-order + 33-group pad ----
#pragma unroll
        for (int s = 0; s < 8; ++s) {
            int c = 2 * s + hf;
            *reinterpret_cast<half8*>(&fkT[wave][(c * 33 + l31) * 8]) = frag[s];
        }

        // gram = FK @ FK^T (f16 in, fp32 acc)
        f32x16 acc;
#pragma unroll
        for (int i = 0; i < 16; ++i) acc[i] = 0.0f;
#pragma unroll
        for (int s = 0; s < 8; ++s)
            acc = __builtin_amdgcn_mfma_f32_32x32x16_f16(frag[s], frag[s], acc, 0, 0, 0);

        // sq via fdot2 (VALU, overlaps MFMAs; no acc dependency)
        float sqp = 0.0f;
#pragma unroll
        for (int s = 0; s < 8; ++s) {
            const half2v* p2 = reinterpret_cast<const half2v*>(&frag[s]);
#pragma unroll
            for (int q = 0; q < 4; ++q)
                sqp = __builtin_amdgcn_fdot2(p2[q], p2[q], sqp, false);
        }
        float sq = sqp + __shfl_xor(sqp, 32, 64);

        // pipeline stage 2: next node's fragment gather (vid_n has ~300 cyc
        // of cover above; these loads fly across dagg/softmax/epilogue)
        const int   mk_n  = (vid_n < 0) ? 1 : 0;
        half8 frag_n[8];
        if (hn) {
            const int idr_n = mk_n ? 0 : vid_n;
            const half8* bpn = reinterpret_cast<const half8*>(hq + (size_t)idr_n * DIM);
#pragma unroll
            for (int s = 0; s < 8; ++s) frag_n[s] = bpn[2 * s + hf];
        }

        // 9th MFMA: acc += -(sq_m + sq_c)/2 -> acc = -d2/2 (hi/lo f16 split)
        {
            _Float16 shi = (_Float16)sq;
            _Float16 slo = (_Float16)(sq - (float)shi);
            _Float16 nh  = (_Float16)(-0.5f * (float)shi);
            _Float16 nl  = (_Float16)(-0.5f * (float)slo);
            _Float16 z   = (_Float16)0.0f, one = (_Float16)1.0f;
            half8 aext = {z, z, z, z, z, z, z, z};
            half8 bext = {z, z, z, z, z, z, z, z};
            if (hf == 0) {
                aext[0] = nh;  aext[1] = nl;  aext[2] = one; aext[3] = one;
                bext[0] = one; bext[1] = one; bext[2] = nh;  bext[3] = nl;
            }
            acc = __builtin_amdgcn_mfma_f32_32x32x16_f16(aext, bext, acc, 0, 0, 0);
        }

        // dagg[c=l31] = sum_m w[m]*dist[m][c]; w[rD] via bpermute; 4-way tree
        float pt[4] = {0.0f, 0.0f, 0.0f, 0.0f};
#pragma unroll
        for (int reg = 0; reg < 16; ++reg) {
            const int c = (reg & 3) + 8 * (reg >> 2);
            float wr = __shfl(wc, pbase + c, 64);        // w[c + 4hf]
            float d2 = fmaxf(-(acc[reg] + acc[reg]), 0.0f);
            float ds = (d2 > 1e-4f) ? __builtin_amdgcn_sqrtf(d2) : 0.0f;
            pt[reg & 3] = fmaf(wr, ds, pt[reg & 3]);
        }
        float part = (pt[0] + pt[1]) + (pt[2] + pt[3]);
        float sA = part + __shfl_xor(part, 32, 64);
        if (mkc || !(sA < 3.4028235e38f)) sA = 3.4028235e38f;

        // fused softmax + weight correction: r = e*w / sum(e*w)
        float x  = -sA;
        float mx = x;
#pragma unroll
        for (int o = 16; o > 0; o >>= 1) mx = fmaxf(mx, __shfl_xor(mx, o, 32));
        float t  = __expf(x - mx) * wc;      // masked lanes: w=0 -> t=0
        float st = t;
#pragma unroll
        for (int o = 16; o > 0; o >>= 1) st += __shfl_xor(st, o, 32);
        float r = t * __builtin_amdgcn_rcpf(st);

        // broadcast r via LDS (dup-write from both halves; benign)
        rbuf[wave][l31] = r;

        // ---- epilogue: out[d] = sum_k r_k * fk[k][d]; 2 dims/lane ----
        float o0 = 0.0f, o1 = 0.0f;
#pragma unroll
        for (int q = 0; q < 8; ++q) {
            float4 rv = rb[q];
            half2v h0 = *reinterpret_cast<const half2v*>(fb + 8 * (4 * q + 0));
            half2v h1 = *reinterpret_cast<const half2v*>(fb + 8 * (4 * q + 1));
            half2v h2 = *reinterpret_cast<const half2v*>(fb + 8 * (4 * q + 2));
            half2v h3 = *reinterpret_cast<const half2v*>(fb + 8 * (4 * q + 3));
            o0 = fmaf(rv.x, (float)h0[0], o0); o1 = fmaf(rv.x, (float)h0[1], o1);
            o0 = fmaf(rv.y, (float)h1[0], o0); o1 = fmaf(rv.y, (float)h1[1], o1);
            o0 = fmaf(rv.z, (float)h2[0], o0); o1 = fmaf(rv.z, (float)h2[1], o1);
            o0 = fmaf(rv.w, (float)h3[0], o0); o1 = fmaf(rv.w, (float)h3[1], o1);
        }
        float2 ov = { o0 + bv.x, o1 + bv.y };
        *reinterpret_cast<float2*>(out + (size_t)nd * DIM + d0) = ov;

        if (!hn) break;
        // rotate pipeline registers
        nd  = ndn;
        mkc = mk_n;
        wc  = mk_n ? 0.0f : tw_n;
#pragma unroll
        for (int s = 0; s < 8; ++s) frag[s] = frag_n[s];
    }
}

extern "C" void kernel_launch(void* const* d_in, const int* in_sizes, int n_in,
                              void* d_out, int out_size, void* d_ws, size_t ws_size,
                              hipStream_t stream) {
    const float* feat = (const float*)d_in[0];
    const float* W    = (const float*)d_in[1];
    const float* bias = (const float*)d_in[2];
    const float* tkw  = (const float*)d_in[3];
    const int*   idx  = (const int*)d_in[4];
    float* out = (float*)d_out;

    const int n = in_sizes[0] / DIM;                       // 50000
    _Float16* hq = (_Float16*)d_ws;                        // n*128*2 = 12.8 MB
    _Float16* wt = hq + (size_t)n * DIM;                   // 32 KB

    const int gblocks = (n + 31) / 32;                     // 1563
    prep<<<64, 256, 0, stream>>>(W, wt);
    gemm128<<<gblocks, 64, 0, stream>>>(feat, wt, hq, n);
    softk<<<gblocks, 128, 0, stream>>>(hq, bias, tkw, idx, out, n);
}

// Round 11
// 158.362 us; speedup vs baseline: 1.0360x; 1.0360x over previous
//
#include <hip/hip_runtime.h>
#include <math.h>

// SoftKConv, round 11.
// r10 post-mortem: persistent grid of 1563 blocks was BELOW the 9-blocks/CU
// LDS residency cap -> occupancy fell 40->25% and softk regressed. The
// pipeline itself was fine (no spill, VGPR 64). r11 = r10 kernel unchanged,
// softk grid = 2560 persistent blocks (10/CU: 9 resident by LDS 17408 B,
// 1 queued to smooth the ~10-nodes/wave imbalance). Expect occ -> ~56%,
// softk -> ~45-52 us.

typedef __attribute__((ext_vector_type(2)))  _Float16 half2v;
typedef __attribute__((ext_vector_type(4)))  _Float16 half4v;
typedef __attribute__((ext_vector_type(8)))  _Float16 half8;
typedef __attribute__((ext_vector_type(16))) float    f32x16;

#define NK   32
#define DIM  128
// LDS: half-offset(k,d) = ((d>>3)*33 + k)*8 + (d&7); 16*33*8 = 4224 halves.
#define FKT_SZ 4224

// ---------------- Kernel 0: WT[n][k] = (f16) W[k][n] -----------------------
__global__ __launch_bounds__(256) void prep(const float* __restrict__ W,
                                            _Float16* __restrict__ WT) {
    int t  = blockIdx.x * 256 + threadIdx.x;   // 0..16383
    int nn = t >> 7, k = t & 127;
    WT[t] = (_Float16)W[k * 128 + nn];
}

// ---------------- Kernel 1: h = feat @ W -> f16, MFMA ----------------------
// 64-thread blocks (1 wave, 32 rows) for fine-grained scheduling.
__global__ __launch_bounds__(64) void gemm128(
    const float* __restrict__ A, const _Float16* __restrict__ WT,
    _Float16* __restrict__ Hq, int n)
{
    const int lane = threadIdx.x;
    const int l31  = lane & 31;
    const int hf   = lane >> 5;

    const int row  = blockIdx.x * 32 + l31;
    const int rowc = row < n ? row : n - 1;

    f32x16 acc[4];
#pragma unroll
    for (int t = 0; t < 4; ++t)
#pragma unroll
        for (int i = 0; i < 16; ++i) acc[t][i] = 0.0f;

    const float* ap = A + (size_t)rowc * 128 + 8 * hf;
#pragma unroll
    for (int s = 0; s < 8; ++s) {
        float4 b0 = *reinterpret_cast<const float4*>(ap + 16 * s);
        float4 b1 = *reinterpret_cast<const float4*>(ap + 16 * s + 4);
        half8 bf;
        bf[0] = (_Float16)b0.x; bf[1] = (_Float16)b0.y;
        bf[2] = (_Float16)b0.z; bf[3] = (_Float16)b0.w;
        bf[4] = (_Float16)b1.x; bf[5] = (_Float16)b1.y;
        bf[6] = (_Float16)b1.z; bf[7] = (_Float16)b1.w;
#pragma unroll
        for (int t = 0; t < 4; ++t) {
            half8 af = *reinterpret_cast<const half8*>(
                WT + (size_t)(l31 + 32 * t) * 128 + 16 * s + 8 * hf);
            acc[t] = __builtin_amdgcn_mfma_f32_32x32x16_f16(af, bf, acc[t], 0, 0, 0);
        }
    }

    if (row < n) {
        _Float16* hp = Hq + (size_t)row * 128;
#pragma unroll
        for (int t = 0; t < 4; ++t)
#pragma unroll
            for (int g = 0; g < 4; ++g) {
                half4v hv;
#pragma unroll
                for (int q = 0; q < 4; ++q) hv[q] = (_Float16)acc[t][4 * g + q];
                *reinterpret_cast<half4v*>(hp + 32 * t + 8 * g + 4 * hf) = hv;
            }
    }
}

// ---------------- Kernel 2: per-node soft medoid, persistent+pipelined -----
// 128 threads = 2 waves; each wave grid-strides over nodes independently
// (no barriers, per-wave LDS region).
__global__ __launch_bounds__(128, 4) void softk(
    const _Float16* __restrict__ hq, const float* __restrict__ bias,
    const float* __restrict__ tkw, const int* __restrict__ idx,
    float* __restrict__ out, int n)
{
    __shared__ __align__(16) _Float16 fkT[2][FKT_SZ];   // 16896 B
    __shared__ __align__(16) float    rbuf[2][NK];      //   256 B

    const int wave = threadIdx.x >> 6;
    const int lane = threadIdx.x & 63;
    const int l31  = lane & 31;
    const int hf   = lane >> 5;
    const int pbase = (lane & 32) + ((lane & 32) >> 3);  // hf=0 -> 0, hf=1 -> 36

    // loop-invariant per-lane state
    const int d0 = 2 * lane;
    const float2 bv = *reinterpret_cast<const float2*>(bias + d0);
    const _Float16* fb = &fkT[wave][((d0 >> 3) * 33) * 8 + (d0 & 7)];
    const float4* rb = reinterpret_cast<const float4*>(&rbuf[wave][0]);

    const int stride = gridDim.x * 2;
    int nd = blockIdx.x * 2 + wave;
    if (nd >= n) return;                    // wave-uniform; no barriers used

    // ---- prologue: loads for first node ----
    int   vid = idx[(size_t)nd * NK + l31];
    float tw  = tkw[(size_t)nd * NK + l31];
    int   mkc = (vid < 0) ? 1 : 0;
    float wc  = mkc ? 0.0f : tw;
    half8 frag[8];
    {
        const int idr = mkc ? 0 : vid;
        const half8* bp = reinterpret_cast<const half8*>(hq + (size_t)idr * DIM);
#pragma unroll
        for (int s = 0; s < 8; ++s) frag[s] = bp[2 * s + hf];
    }

    while (true) {
        const int  ndn = nd + stride;
        const bool hn  = ndn < n;

        // pipeline stage 1: next node's idx/tkw (cover = staging+gram+fdot2)
        int vid_n = 0; float tw_n = 0.0f;
        if (hn) {
            vid_n = idx[(size_t)ndn * NK + l31];
            tw_n  = tkw[(size_t)ndn * NK + l31];
        }

        // ---- stage frags to LDS, fragment-order + 33-group pad ----
#pragma unroll
        for (int s = 0; s < 8; ++s) {
            int c = 2 * s + hf;
            *reinterpret_cast<half8*>(&fkT[wave][(c * 33 + l31) * 8]) = frag[s];
        }

        // gram = FK @ FK^T (f16 in, fp32 acc)
        f32x16 acc;
#pragma unroll
        for (int i = 0; i < 16; ++i) acc[i] = 0.0f;
#pragma unroll
        for (int s = 0; s < 8; ++s)
            acc = __builtin_amdgcn_mfma_f32_32x32x16_f16(frag[s], frag[s], acc, 0, 0, 0);

        // sq via fdot2 (VALU, overlaps MFMAs; no acc dependency)
        float sqp = 0.0f;
#pragma unroll
        for (int s = 0; s < 8; ++s) {
            const half2v* p2 = reinterpret_cast<const half2v*>(&frag[s]);
#pragma unroll
            for (int q = 0; q < 4; ++q)
                sqp = __builtin_amdgcn_fdot2(p2[q], p2[q], sqp, false);
        }
        float sq = sqp + __shfl_xor(sqp, 32, 64);

        // pipeline stage 2: next node's fragment gather (vid_n has ~300 cyc
        // of cover above; these loads fly across dagg/softmax/epilogue)
        const int   mk_n  = (vid_n < 0) ? 1 : 0;
        half8 frag_n[8];
        if (hn) {
            const int idr_n = mk_n ? 0 : vid_n;
            const half8* bpn = reinterpret_cast<const half8*>(hq + (size_t)idr_n * DIM);
#pragma unroll
            for (int s = 0; s < 8; ++s) frag_n[s] = bpn[2 * s + hf];
        }

        // 9th MFMA: acc += -(sq_m + sq_c)/2 -> acc = -d2/2 (hi/lo f16 split)
        {
            _Float16 shi = (_Float16)sq;
            _Float16 slo = (_Float16)(sq - (float)shi);
            _Float16 nh  = (_Float16)(-0.5f * (float)shi);
            _Float16 nl  = (_Float16)(-0.5f * (float)slo);
            _Float16 z   = (_Float16)0.0f, one = (_Float16)1.0f;
            half8 aext = {z, z, z, z, z, z, z, z};
            half8 bext = {z, z, z, z, z, z, z, z};
            if (hf == 0) {
                aext[0] = nh;  aext[1] = nl;  aext[2] = one; aext[3] = one;
                bext[0] = one; bext[1] = one; bext[2] = nh;  bext[3] = nl;
            }
            acc = __builtin_amdgcn_mfma_f32_32x32x16_f16(aext, bext, acc, 0, 0, 0);
        }

        // dagg[c=l31] = sum_m w[m]*dist[m][c]; w[rD] via bpermute; 4-way tree
        float pt[4] = {0.0f, 0.0f, 0.0f, 0.0f};
#pragma unroll
        for (int reg = 0; reg < 16; ++reg) {
            const int c = (reg & 3) + 8 * (reg >> 2);
            float wr = __shfl(wc, pbase + c, 64);        // w[c + 4hf]
            float d2 = fmaxf(-(acc[reg] + acc[reg]), 0.0f);
            float ds = (d2 > 1e-4f) ? __builtin_amdgcn_sqrtf(d2) : 0.0f;
            pt[reg & 3] = fmaf(wr, ds, pt[reg & 3]);
        }
        float part = (pt[0] + pt[1]) + (pt[2] + pt[3]);
        float sA = part + __shfl_xor(part, 32, 64);
        if (mkc || !(sA < 3.4028235e38f)) sA = 3.4028235e38f;

        // fused softmax + weight correction: r = e*w / sum(e*w)
        float x  = -sA;
        float mx = x;
#pragma unroll
        for (int o = 16; o > 0; o >>= 1) mx = fmaxf(mx, __shfl_xor(mx, o, 32));
        float t  = __expf(x - mx) * wc;      // masked lanes: w=0 -> t=0
        float st = t;
#pragma unroll
        for (int o = 16; o > 0; o >>= 1) st += __shfl_xor(st, o, 32);
        float r = t * __builtin_amdgcn_rcpf(st);

        // broadcast r via LDS (dup-write from both halves; benign)
        rbuf[wave][l31] = r;

        // ---- epilogue: out[d] = sum_k r_k * fk[k][d]; 2 dims/lane ----
        float o0 = 0.0f, o1 = 0.0f;
#pragma unroll
        for (int q = 0; q < 8; ++q) {
            float4 rv = rb[q];
            half2v h0 = *reinterpret_cast<const half2v*>(fb + 8 * (4 * q + 0));
            half2v h1 = *reinterpret_cast<const half2v*>(fb + 8 * (4 * q + 1));
            half2v h2 = *reinterpret_cast<const half2v*>(fb + 8 * (4 * q + 2));
            half2v h3 = *reinterpret_cast<const half2v*>(fb + 8 * (4 * q + 3));
            o0 = fmaf(rv.x, (float)h0[0], o0); o1 = fmaf(rv.x, (float)h0[1], o1);
            o0 = fmaf(rv.y, (float)h1[0], o0); o1 = fmaf(rv.y, (float)h1[1], o1);
            o0 = fmaf(rv.z, (float)h2[0], o0); o1 = fmaf(rv.z, (float)h2[1], o1);
            o0 = fmaf(rv.w, (float)h3[0], o0); o1 = fmaf(rv.w, (float)h3[1], o1);
        }
        float2 ov = { o0 + bv.x, o1 + bv.y };
        *reinterpret_cast<float2*>(out + (size_t)nd * DIM + d0) = ov;

        if (!hn) break;
        // rotate pipeline registers
        nd  = ndn;
        mkc = mk_n;
        wc  = mk_n ? 0.0f : tw_n;
#pragma unroll
        for (int s = 0; s < 8; ++s) frag[s] = frag_n[s];
    }
}

extern "C" void kernel_launch(void* const* d_in, const int* in_sizes, int n_in,
                              void* d_out, int out_size, void* d_ws, size_t ws_size,
                              hipStream_t stream) {
    const float* feat = (const float*)d_in[0];
    const float* W    = (const float*)d_in[1];
    const float* bias = (const float*)d_in[2];
    const float* tkw  = (const float*)d_in[3];
    const int*   idx  = (const int*)d_in[4];
    float* out = (float*)d_out;

    const int n = in_sizes[0] / DIM;                       // 50000
    _Float16* hq = (_Float16*)d_ws;                        // n*128*2 = 12.8 MB
    _Float16* wt = hq + (size_t)n * DIM;                   // 32 KB

    const int gblocks = (n + 31) / 32;                     // 1563 (gemm)
    // softk: persistent grid sized ABOVE the LDS residency cap (9 blocks/CU
    // x 256 CU = 2304 resident; +1/CU queued to smooth imbalance).
    int sblocks = 2560;
    if (sblocks > (n + 1) / 2) sblocks = (n + 1) / 2;

    prep<<<64, 256, 0, stream>>>(W, wt);
    gemm128<<<gblocks, 64, 0, stream>>>(feat, wt, hq, n);
    softk<<<sblocks, 128, 0, stream>>>(hq, bias, tkw, idx, out, n);
}

// Round 12
// 153.982 us; speedup vs baseline: 1.0655x; 1.0284x over previous
//
#include <hip/hip_runtime.h>
#include <math.h>

// SoftKConv, round 12.
// r11 post-mortem: persistence caps occupancy (~30%, CP-refill lost); r9's
// refill gave 40% but had NO pipeline, so each node paid the serial
// idx->gather chain (~1200-1800 cyc, the ~90% per-wave stall). r12 runs
// BOTH for the first time: r10's pipelined wave body, 64-thread blocks
// (8704 B LDS -> ~13 waves/CU cap), grid = ceil(n/4) = 12500 short-lived
// blocks (~4 nodes/wave: 3/4 gathers hidden, CP refill keeps residency).

typedef __attribute__((ext_vector_type(2)))  _Float16 half2v;
typedef __attribute__((ext_vector_type(4)))  _Float16 half4v;
typedef __attribute__((ext_vector_type(8)))  _Float16 half8;
typedef __attribute__((ext_vector_type(16))) float    f32x16;

#define NK   32
#define DIM  128
// LDS: half-offset(k,d) = ((d>>3)*33 + k)*8 + (d&7); 16*33*8 = 4224 halves.
#define FKT_SZ 4224

// ---------------- Kernel 0: WT[n][k] = (f16) W[k][n] -----------------------
__global__ __launch_bounds__(256) void prep(const float* __restrict__ W,
                                            _Float16* __restrict__ WT) {
    int t  = blockIdx.x * 256 + threadIdx.x;   // 0..16383
    int nn = t >> 7, k = t & 127;
    WT[t] = (_Float16)W[k * 128 + nn];
}

// ---------------- Kernel 1: h = feat @ W -> f16, MFMA ----------------------
__global__ __launch_bounds__(64) void gemm128(
    const float* __restrict__ A, const _Float16* __restrict__ WT,
    _Float16* __restrict__ Hq, int n)
{
    const int lane = threadIdx.x;
    const int l31  = lane & 31;
    const int hf   = lane >> 5;

    const int row  = blockIdx.x * 32 + l31;
    const int rowc = row < n ? row : n - 1;

    f32x16 acc[4];
#pragma unroll
    for (int t = 0; t < 4; ++t)
#pragma unroll
        for (int i = 0; i < 16; ++i) acc[t][i] = 0.0f;

    const float* ap = A + (size_t)rowc * 128 + 8 * hf;
#pragma unroll
    for (int s = 0; s < 8; ++s) {
        float4 b0 = *reinterpret_cast<const float4*>(ap + 16 * s);
        float4 b1 = *reinterpret_cast<const float4*>(ap + 16 * s + 4);
        half8 bf;
        bf[0] = (_Float16)b0.x; bf[1] = (_Float16)b0.y;
        bf[2] = (_Float16)b0.z; bf[3] = (_Float16)b0.w;
        bf[4] = (_Float16)b1.x; bf[5] = (_Float16)b1.y;
        bf[6] = (_Float16)b1.z; bf[7] = (_Float16)b1.w;
#pragma unroll
        for (int t = 0; t < 4; ++t) {
            half8 af = *reinterpret_cast<const half8*>(
                WT + (size_t)(l31 + 32 * t) * 128 + 16 * s + 8 * hf);
            acc[t] = __builtin_amdgcn_mfma_f32_32x32x16_f16(af, bf, acc[t], 0, 0, 0);
        }
    }

    if (row < n) {
        _Float16* hp = Hq + (size_t)row * 128;
#pragma unroll
        for (int t = 0; t < 4; ++t)
#pragma unroll
            for (int g = 0; g < 4; ++g) {
                half4v hv;
#pragma unroll
                for (int q = 0; q < 4; ++q) hv[q] = (_Float16)acc[t][4 * g + q];
                *reinterpret_cast<half4v*>(hp + 32 * t + 8 * g + 4 * hf) = hv;
            }
    }
}

// ---------------- Kernel 2: per-node soft medoid, pipelined ----------------
// 64 threads = 1 wave per block; grid-strides over ~4 nodes with next-node
// prefetch. No barriers (single wave, LDS in-order).
__global__ __launch_bounds__(64, 4) void softk(
    const _Float16* __restrict__ hq, const float* __restrict__ bias,
    const float* __restrict__ tkw, const int* __restrict__ idx,
    float* __restrict__ out, int n)
{
    __shared__ __align__(16) _Float16 fkT[FKT_SZ];   // 8448 B
    __shared__ __align__(16) float    rbuf[NK];      //  128 B

    const int lane = threadIdx.x;
    const int l31  = lane & 31;
    const int hf   = lane >> 5;
    const int pbase = (lane & 32) + ((lane & 32) >> 3);  // hf=0 -> 0, hf=1 -> 36

    // loop-invariant per-lane state
    const int d0 = 2 * lane;
    const float2 bv = *reinterpret_cast<const float2*>(bias + d0);
    const _Float16* fb = &fkT[((d0 >> 3) * 33) * 8 + (d0 & 7)];
    const float4* rb = reinterpret_cast<const float4*>(&rbuf[0]);

    const int stride = gridDim.x;
    int nd = blockIdx.x;
    if (nd >= n) return;

    // ---- prologue: loads for first node ----
    int   vid = idx[(size_t)nd * NK + l31];
    float tw  = tkw[(size_t)nd * NK + l31];
    int   mkc = (vid < 0) ? 1 : 0;
    float wc  = mkc ? 0.0f : tw;
    half8 frag[8];
    {
        const int idr = mkc ? 0 : vid;
        const half8* bp = reinterpret_cast<const half8*>(hq + (size_t)idr * DIM);
#pragma unroll
        for (int s = 0; s < 8; ++s) frag[s] = bp[2 * s + hf];
    }

    while (true) {
        const int  ndn = nd + stride;
        const bool hn  = ndn < n;

        // pipeline stage 1: next node's idx/tkw (cover = staging+gram+fdot2)
        int vid_n = 0; float tw_n = 0.0f;
        if (hn) {
            vid_n = idx[(size_t)ndn * NK + l31];
            tw_n  = tkw[(size_t)ndn * NK + l31];
        }

        // ---- stage frags to LDS, fragment-order + 33-group pad ----
#pragma unroll
        for (int s = 0; s < 8; ++s) {
            int c = 2 * s + hf;
            *reinterpret_cast<half8*>(&fkT[(c * 33 + l31) * 8]) = frag[s];
        }

        // gram = FK @ FK^T (f16 in, fp32 acc)
        f32x16 acc;
#pragma unroll
        for (int i = 0; i < 16; ++i) acc[i] = 0.0f;
#pragma unroll
        for (int s = 0; s < 8; ++s)
            acc = __builtin_amdgcn_mfma_f32_32x32x16_f16(frag[s], frag[s], acc, 0, 0, 0);

        // sq via fdot2 (VALU, overlaps MFMAs; no acc dependency)
        float sqp = 0.0f;
#pragma unroll
        for (int s = 0; s < 8; ++s) {
            const half2v* p2 = reinterpret_cast<const half2v*>(&frag[s]);
#pragma unroll
            for (int q = 0; q < 4; ++q)
                sqp = __builtin_amdgcn_fdot2(p2[q], p2[q], sqp, false);
        }
        float sq = sqp + __shfl_xor(sqp, 32, 64);

        // pipeline stage 2: next node's fragment gather (vid_n covered above;
        // these loads stay in flight across dagg/softmax/epilogue)
        const int mk_n = (vid_n < 0) ? 1 : 0;
        half8 frag_n[8];
        if (hn) {
            const int idr_n = mk_n ? 0 : vid_n;
            const half8* bpn = reinterpret_cast<const half8*>(hq + (size_t)idr_n * DIM);
#pragma unroll
            for (int s = 0; s < 8; ++s) frag_n[s] = bpn[2 * s + hf];
        }

        // 9th MFMA: acc += -(sq_m + sq_c)/2 -> acc = -d2/2 (hi/lo f16 split)
        {
            _Float16 shi = (_Float16)sq;
            _Float16 slo = (_Float16)(sq - (float)shi);
            _Float16 nh  = (_Float16)(-0.5f * (float)shi);
            _Float16 nl  = (_Float16)(-0.5f * (float)slo);
            _Float16 z   = (_Float16)0.0f, one = (_Float16)1.0f;
            half8 aext = {z, z, z, z, z, z, z, z};
            half8 bext = {z, z, z, z, z, z, z, z};
            if (hf == 0) {
                aext[0] = nh;  aext[1] = nl;  aext[2] = one; aext[3] = one;
                bext[0] = one; bext[1] = one; bext[2] = nh;  bext[3] = nl;
            }
            acc = __builtin_amdgcn_mfma_f32_32x32x16_f16(aext, bext, acc, 0, 0, 0);
        }

        // dagg[c=l31] = sum_m w[m]*dist[m][c]; w[rD] via bpermute; 4-way tree
        float pt[4] = {0.0f, 0.0f, 0.0f, 0.0f};
#pragma unroll
        for (int reg = 0; reg < 16; ++reg) {
            const int c = (reg & 3) + 8 * (reg >> 2);
            float wr = __shfl(wc, pbase + c, 64);        // w[c + 4hf]
            float d2 = fmaxf(-(acc[reg] + acc[reg]), 0.0f);
            float ds = (d2 > 1e-4f) ? __builtin_amdgcn_sqrtf(d2) : 0.0f;
            pt[reg & 3] = fmaf(wr, ds, pt[reg & 3]);
        }
        float part = (pt[0] + pt[1]) + (pt[2] + pt[3]);
        float sA = part + __shfl_xor(part, 32, 64);
        if (mkc || !(sA < 3.4028235e38f)) sA = 3.4028235e38f;

        // fused softmax + weight correction: r = e*w / sum(e*w)
        float x  = -sA;
        float mx = x;
#pragma unroll
        for (int o = 16; o > 0; o >>= 1) mx = fmaxf(mx, __shfl_xor(mx, o, 32));
        float t  = __expf(x - mx) * wc;      // masked lanes: w=0 -> t=0
        float st = t;
#pragma unroll
        for (int o = 16; o > 0; o >>= 1) st += __shfl_xor(st, o, 32);
        float r = t * __builtin_amdgcn_rcpf(st);

        // broadcast r via LDS (dup-write from both halves; benign)
        rbuf[l31] = r;

        // ---- epilogue: out[d] = sum_k r_k * fk[k][d]; 2 dims/lane ----
        float o0 = 0.0f, o1 = 0.0f;
#pragma unroll
        for (int q = 0; q < 8; ++q) {
            float4 rv = rb[q];
            half2v h0 = *reinterpret_cast<const half2v*>(fb + 8 * (4 * q + 0));
            half2v h1 = *reinterpret_cast<const half2v*>(fb + 8 * (4 * q + 1));
            half2v h2 = *reinterpret_cast<const half2v*>(fb + 8 * (4 * q + 2));
            half2v h3 = *reinterpret_cast<const half2v*>(fb + 8 * (4 * q + 3));
            o0 = fmaf(rv.x, (float)h0[0], o0); o1 = fmaf(rv.x, (float)h0[1], o1);
            o0 = fmaf(rv.y, (float)h1[0], o0); o1 = fmaf(rv.y, (float)h1[1], o1);
            o0 = fmaf(rv.z, (float)h2[0], o0); o1 = fmaf(rv.z, (float)h2[1], o1);
            o0 = fmaf(rv.w, (float)h3[0], o0); o1 = fmaf(rv.w, (float)h3[1], o1);
        }
        float2 ov = { o0 + bv.x, o1 + bv.y };
        *reinterpret_cast<float2*>(out + (size_t)nd * DIM + d0) = ov;

        if (!hn) break;
        // rotate pipeline registers
        nd  = ndn;
        mkc = mk_n;
        wc  = mk_n ? 0.0f : tw_n;
#pragma unroll
        for (int s = 0; s < 8; ++s) frag[s] = frag_n[s];
    }
}

extern "C" void kernel_launch(void* const* d_in, const int* in_sizes, int n_in,
                              void* d_out, int out_size, void* d_ws, size_t ws_size,
                              hipStream_t stream) {
    const float* feat = (const float*)d_in[0];
    const float* W    = (const float*)d_in[1];
    const float* bias = (const float*)d_in[2];
    const float* tkw  = (const float*)d_in[3];
    const int*   idx  = (const int*)d_in[4];
    float* out = (float*)d_out;

    const int n = in_sizes[0] / DIM;                       // 50000
    _Float16* hq = (_Float16*)d_ws;                        // n*128*2 = 12.8 MB
    _Float16* wt = hq + (size_t)n * DIM;                   // 32 KB

    const int gblocks = (n + 31) / 32;                     // 1563 (gemm)
    // softk: 1 wave/block, ~4 nodes/wave -> 12500 short-lived blocks:
    // pipeline hides 3/4 of gather latency, CP refill keeps LDS-capped
    // residency (~13 waves/CU) topped up (r9-style).
    const int sblocks = (n + 3) / 4;

    prep<<<64, 256, 0, stream>>>(W, wt);
    gemm128<<<gblocks, 64, 0, stream>>>(feat, wt, hq, n);
    softk<<<sblocks, 64, 0, stream>>>(hq, bias, tkw, idx, out, n);
}

// Round 13
// 152.791 us; speedup vs baseline: 1.0738x; 1.0078x over previous
//
#include <hip/hip_runtime.h>
#include <math.h>

// SoftKConv, round 13.
// r12 post-mortem: three schedule families converge ~65 us, no pipe >41%.
// Remaining suspect: address-divergent gather (64 lanes x 32 rows per instr
// => ~32 coalescer transactions/instr, ~270/node; TA serializes ~1/cyc).
// r13: COALESCED gather (instr i loads 4 whole rows; 8 transactions/instr),
// redistributed through LDS with a per-row rotation (col' = (c+16(k&3))&63):
//   - writes: 8-lanes-per-4-bank-group = LDS floor (same as before)
//   - MFMA frag b128 reads: bank group (5b+4t+x)%8 uniform = floor
//   - epilogue b32: 64 distinct dwords = 2-way = free; 4 precomputed rotated
//     vaddrs + imm 272*k (zero per-k VALU)
// Bit-identical math to r12. Pipeline + CP-refill grid unchanged.

typedef __attribute__((ext_vector_type(2)))  _Float16 half2v;
typedef __attribute__((ext_vector_type(4)))  _Float16 half4v;
typedef __attribute__((ext_vector_type(8)))  _Float16 half8;
typedef __attribute__((ext_vector_type(16))) float    f32x16;

#define NK   32
#define DIM  128
// LDS row stride 272 B (64 dwords used + 4 pad); rotation 16*(k&3) dwords.
#define ROWB 272

// ---------------- Kernel 0: WT[n][k] = (f16) W[k][n] -----------------------
__global__ __launch_bounds__(256) void prep(const float* __restrict__ W,
                                            _Float16* __restrict__ WT) {
    int t  = blockIdx.x * 256 + threadIdx.x;   // 0..16383
    int nn = t >> 7, k = t & 127;
    WT[t] = (_Float16)W[k * 128 + nn];
}

// ---------------- Kernel 1: h = feat @ W -> f16, MFMA ----------------------
__global__ __launch_bounds__(64) void gemm128(
    const float* __restrict__ A, const _Float16* __restrict__ WT,
    _Float16* __restrict__ Hq, int n)
{
    const int lane = threadIdx.x;
    const int l31  = lane & 31;
    const int hf   = lane >> 5;

    const int row  = blockIdx.x * 32 + l31;
    const int rowc = row < n ? row : n - 1;

    f32x16 acc[4];
#pragma unroll
    for (int t = 0; t < 4; ++t)
#pragma unroll
        for (int i = 0; i < 16; ++i) acc[t][i] = 0.0f;

    const float* ap = A + (size_t)rowc * 128 + 8 * hf;
#pragma unroll
    for (int s = 0; s < 8; ++s) {
        float4 b0 = *reinterpret_cast<const float4*>(ap + 16 * s);
        float4 b1 = *reinterpret_cast<const float4*>(ap + 16 * s + 4);
        half8 bf;
        bf[0] = (_Float16)b0.x; bf[1] = (_Float16)b0.y;
        bf[2] = (_Float16)b0.z; bf[3] = (_Float16)b0.w;
        bf[4] = (_Float16)b1.x; bf[5] = (_Float16)b1.y;
        bf[6] = (_Float16)b1.z; bf[7] = (_Float16)b1.w;
#pragma unroll
        for (int t = 0; t < 4; ++t) {
            half8 af = *reinterpret_cast<const half8*>(
                WT + (size_t)(l31 + 32 * t) * 128 + 16 * s + 8 * hf);
            acc[t] = __builtin_amdgcn_mfma_f32_32x32x16_f16(af, bf, acc[t], 0, 0, 0);
        }
    }

    if (row < n) {
        _Float16* hp = Hq + (size_t)row * 128;
#pragma unroll
        for (int t = 0; t < 4; ++t)
#pragma unroll
            for (int g = 0; g < 4; ++g) {
                half4v hv;
#pragma unroll
                for (int q = 0; q < 4; ++q) hv[q] = (_Float16)acc[t][4 * g + q];
                *reinterpret_cast<half4v*>(hp + 32 * t + 8 * g + 4 * hf) = hv;
            }
    }
}

// ---------------- Kernel 2: per-node soft medoid, pipelined ----------------
// 64 threads = 1 wave/block; ~4 nodes/wave with next-node prefetch.
__global__ __launch_bounds__(64, 4) void softk(
    const _Float16* __restrict__ hq, const float* __restrict__ bias,
    const float* __restrict__ tkw, const int* __restrict__ idx,
    float* __restrict__ out, int n)
{
    __shared__ __align__(16) char  fkT[NK * ROWB];   // 8704 B, rotated rows
    __shared__ __align__(16) float rbuf[NK];         //  128 B

    const int lane = threadIdx.x;
    const int l31  = lane & 31;
    const int hf   = lane >> 5;
    const int g    = lane >> 4;        // gather row group 0..3
    const int m    = lane & 15;        // gather 16B chunk 0..15
    const int pbase = (lane & 32) + ((lane & 32) >> 3);

    // loop-invariant addresses
    const int d0 = 2 * lane;
    const float2 bv = *reinterpret_cast<const float2*>(bias + d0);
    const float4* rb = reinterpret_cast<const float4*>(&rbuf[0]);
    // coalesced-write vaddr: row k=4i+g, cols 4m..4m+3 -> 272k + 16*((m+4g)&15)
    const int wbase = ROWB * g + 16 * ((m + 4 * g) & 15);
    // frag-read base (row l31) and rolling rotated column
    const int fbase = ROWB * l31;
    const int uc0   = 4 * hf + 16 * (l31 & 3);       // dword col bias
    // epilogue vaddrs: col lane of row k stored at ((lane + 16*(k&3))&63)
    int eaddr[4];
#pragma unroll
    for (int p = 0; p < 4; ++p) eaddr[p] = 4 * ((lane + 16 * p) & 63);

    const int stride = gridDim.x;
    int nd = blockIdx.x;
    if (nd >= n) return;

    // ---- prologue: first node's idx/tkw + coalesced gather ----
    int   vid = idx[(size_t)nd * NK + l31];
    float tw  = tkw[(size_t)nd * NK + l31];
    int   mkc = (vid < 0) ? 1 : 0;
    float wc  = mkc ? 0.0f : tw;
    half8 gb[8];
    {
        int idr = mkc ? 0 : vid;                     // per-lane (k=l31) id
#pragma unroll
        for (int i = 0; i < 8; ++i) {
            int idg = __shfl(idr, 4 * i + g, 64);    // row 4i+g's id
            gb[i] = *reinterpret_cast<const half8*>(
                hq + (size_t)idg * DIM + 8 * m);     // lane's 16B of that row
        }
    }

    while (true) {
        const int  ndn = nd + stride;
        const bool hn  = ndn < n;

        // pipeline stage 1: next node's idx/tkw
        int vid_n = 0; float tw_n = 0.0f;
        if (hn) {
            vid_n = idx[(size_t)ndn * NK + l31];
            tw_n  = tkw[(size_t)ndn * NK + l31];
        }

        // ---- coalesced write of gathered rows into rotated LDS ----
#pragma unroll
        for (int i = 0; i < 8; ++i)
            *reinterpret_cast<half8*>(&fkT[1088 * i + wbase]) = gb[i];

        // ---- frag reads (row l31, rotated) + gram MFMA + fdot2 sq ----
        f32x16 acc;
#pragma unroll
        for (int i = 0; i < 16; ++i) acc[i] = 0.0f;
        float sqp = 0.0f;
        int u = uc0;
#pragma unroll
        for (int s = 0; s < 8; ++s) {
            half8 fr = *reinterpret_cast<const half8*>(&fkT[fbase + 4 * (u & 63)]);
            u += 8;
            acc = __builtin_amdgcn_mfma_f32_32x32x16_f16(fr, fr, acc, 0, 0, 0);
            const half2v* p2 = reinterpret_cast<const half2v*>(&fr);
#pragma unroll
            for (int q = 0; q < 4; ++q)
                sqp = __builtin_amdgcn_fdot2(p2[q], p2[q], sqp, false);
        }
        float sq = sqp + __shfl_xor(sqp, 32, 64);

        // pipeline stage 2: next node's coalesced gather (in flight across
        // the dagg/softmax/epilogue tail)
        const int mk_n = (vid_n < 0) ? 1 : 0;
        half8 gb_n[8];
        if (hn) {
            int idr_n = mk_n ? 0 : vid_n;
#pragma unroll
            for (int i = 0; i < 8; ++i) {
                int idg = __shfl(idr_n, 4 * i + g, 64);
                gb_n[i] = *reinterpret_cast<const half8*>(
                    hq + (size_t)idg * DIM + 8 * m);
            }
        }

        // 9th MFMA: acc += -(sq_m + sq_c)/2 -> acc = -d2/2 (hi/lo f16 split)
        {
            _Float16 shi = (_Float16)sq;
            _Float16 slo = (_Float16)(sq - (float)shi);
            _Float16 nh  = (_Float16)(-0.5f * (float)shi);
            _Float16 nl  = (_Float16)(-0.5f * (float)slo);
            _Float16 z   = (_Float16)0.0f, one = (_Float16)1.0f;
            half8 aext = {z, z, z, z, z, z, z, z};
            half8 bext = {z, z, z, z, z, z, z, z};
            if (hf == 0) {
                aext[0] = nh;  aext[1] = nl;  aext[2] = one; aext[3] = one;
                bext[0] = one; bext[1] = one; bext[2] = nh;  bext[3] = nl;
            }
            acc = __builtin_amdgcn_mfma_f32_32x32x16_f16(aext, bext, acc, 0, 0, 0);
        }

        // dagg[c=l31] = sum_m w[m]*dist[m][c]; w[rD] via bpermute; 4-way tree
        float pt[4] = {0.0f, 0.0f, 0.0f, 0.0f};
#pragma unroll
        for (int reg = 0; reg < 16; ++reg) {
            const int c = (reg & 3) + 8 * (reg >> 2);
            float wr = __shfl(wc, pbase + c, 64);        // w[c + 4hf]
            float d2 = fmaxf(-(acc[reg] + acc[reg]), 0.0f);
            float ds = (d2 > 1e-4f) ? __builtin_amdgcn_sqrtf(d2) : 0.0f;
            pt[reg & 3] = fmaf(wr, ds, pt[reg & 3]);
        }
        float part = (pt[0] + pt[1]) + (pt[2] + pt[3]);
        float sA = part + __shfl_xor(part, 32, 64);
        if (mkc || !(sA < 3.4028235e38f)) sA = 3.4028235e38f;

        // fused softmax + weight correction: r = e*w / sum(e*w)
        float x  = -sA;
        float mx = x;
#pragma unroll
        for (int o = 16; o > 0; o >>= 1) mx = fmaxf(mx, __shfl_xor(mx, o, 32));
        float t  = __expf(x - mx) * wc;      // masked lanes: w=0 -> t=0
        float st = t;
#pragma unroll
        for (int o = 16; o > 0; o >>= 1) st += __shfl_xor(st, o, 32);
        float r = t * __builtin_amdgcn_rcpf(st);

        // broadcast r via LDS (dup-write from both halves; benign)
        rbuf[l31] = r;

        // ---- epilogue: out[d] = sum_k r_k * fk[k][d]; 2 dims/lane ----
        // lane's dword (cols d0,d0+1) of row k at eaddr[k&3] + 272k (imm).
        float o0 = 0.0f, o1 = 0.0f;
#pragma unroll
        for (int q = 0; q < 8; ++q) {
            float4 rv = rb[q];
            half2v h0 = *reinterpret_cast<const half2v*>(&fkT[ROWB * (4 * q + 0) + eaddr[0]]);
            half2v h1 = *reinterpret_cast<const half2v*>(&fkT[ROWB * (4 * q + 1) + eaddr[1]]);
            half2v h2 = *reinterpret_cast<const half2v*>(&fkT[ROWB * (4 * q + 2) + eaddr[2]]);
            half2v h3 = *reinterpret_cast<const half2v*>(&fkT[ROWB * (4 * q + 3) + eaddr[3]]);
            o0 = fmaf(rv.x, (float)h0[0], o0); o1 = fmaf(rv.x, (float)h0[1], o1);
            o0 = fmaf(rv.y, (float)h1[0], o0); o1 = fmaf(rv.y, (float)h1[1], o1);
            o0 = fmaf(rv.z, (float)h2[0], o0); o1 = fmaf(rv.z, (float)h2[1], o1);
            o0 = fmaf(rv.w, (float)h3[0], o0); o1 = fmaf(rv.w, (float)h3[1], o1);
        }
        float2 ov = { o0 + bv.x, o1 + bv.y };
        *reinterpret_cast<float2*>(out + (size_t)nd * DIM + d0) = ov;

        if (!hn) break;
        // rotate pipeline registers
        nd  = ndn;
        mkc = mk_n;
        wc  = mk_n ? 0.0f : tw_n;
#pragma unroll
        for (int i = 0; i < 8; ++i) gb[i] = gb_n[i];
    }
}

extern "C" void kernel_launch(void* const* d_in, const int* in_sizes, int n_in,
                              void* d_out, int out_size, void* d_ws, size_t ws_size,
                              hipStream_t stream) {
    const float* feat = (const float*)d_in[0];
    const float* W    = (const float*)d_in[1];
    const float* bias = (const float*)d_in[2];
    const float* tkw  = (const float*)d_in[3];
    const int*   idx  = (const int*)d_in[4];
    float* out = (float*)d_out;

    const int n = in_sizes[0] / DIM;                       // 50000
    _Float16* hq = (_Float16*)d_ws;                        // n*128*2 = 12.8 MB
    _Float16* wt = hq + (size_t)n * DIM;                   // 32 KB

    const int gblocks = (n + 31) / 32;                     // 1563 (gemm)
    const int sblocks = (n + 3) / 4;                       // 12500 (softk)

    prep<<<64, 256, 0, stream>>>(W, wt);
    gemm128<<<gblocks, 64, 0, stream>>>(feat, wt, hq, n);
    softk<<<sblocks, 64, 0, stream>>>(hq, bias, tkw, idx, out, n);
}